// Round 8
// baseline (220.322 us; speedup 1.0000x reference)
//
#include <hip/hip_runtime.h>
#include <hip/hip_fp16.h>
#include <math.h>

#define N_NODES 100000
#define N_EDGES 1000000
#define N_GRAPHS 1024
#define BN_EPS 1e-5f

#define BUCKET_NODES 128
#define NB_BUCKETS ((N_NODES + BUCKET_NODES - 1) / BUCKET_NODES)  // 782
#define BUCKET_PAD 2048   // fixed per-bucket slot; counts ~Poisson(1280), >20 sigma margin
#define BUCKET_CAP 3072
#define SCAT_CHUNK 2048

typedef __attribute__((__ext_vector_type__(8))) _Float16 f16x8;
typedef __attribute__((__ext_vector_type__(4))) _Float16 f16x4;
typedef __attribute__((__ext_vector_type__(4))) float f32x4;

// ---------- helpers ----------
static __device__ __forceinline__ float elu_f(float v) {
    return v > 0.f ? v : expm1f(v);
}

// packed fp16 max (2 halves) — gfx950 v_pk_max_f16
static __device__ __forceinline__ unsigned pkmax(unsigned a, unsigned b) {
    unsigned r;
    asm("v_pk_max_f16 %0, %1, %2" : "=v"(r) : "v"(a), "v"(b));
    return r;
}
#define HALF2_NEG_INF 0xFC00FC00u

static __device__ __forceinline__ uint4 pkmax4(uint4 a, uint4 b) {
    uint4 r;
    r.x = pkmax(a.x, b.x);
    r.y = pkmax(a.y, b.y);
    r.z = pkmax(a.z, b.z);
    r.w = pkmax(a.w, b.w);
    return r;
}

// monotone float -> uint mapping (order-preserving) for atomicMax on floats
static __device__ __forceinline__ unsigned fmap(float f) {
    unsigned u = __float_as_uint(f);
    return (u & 0x80000000u) ? ~u : (u | 0x80000000u);
}
static __device__ __forceinline__ float funmap(unsigned u) {
    unsigned b = (u & 0x80000000u) ? (u & 0x7FFFFFFFu) : ~u;
    return __uint_as_float(b);
}
#define NEG_INF_MAPPED 0x007FFFFFu  // fmap(-inf)

// ---------- prep: fragment-order fp16 weight blobs + biases + cursor/pooled init ----------
__global__ __launch_bounds__(256) void prep_kernel(
        const float* __restrict__ Wt1, const float* __restrict__ bt1,
        const float* __restrict__ Wp1, const float* __restrict__ bp1,
        const float* __restrict__ gamma, const float* __restrict__ beta,
        const float* __restrict__ mean,  const float* __restrict__ var,
        const float* __restrict__ Wt2, const float* __restrict__ bt2,
        const float* __restrict__ Wp2, const float* __restrict__ bp2,
        const float* __restrict__ Wt3, const float* __restrict__ bt3,
        const float* __restrict__ Wp3, const float* __restrict__ bp3,
        __half* __restrict__ wsz1, float* __restrict__ qb1,
        __half* __restrict__ wsz2, float* __restrict__ qb2,
        __half* __restrict__ wsz3, float* __restrict__ qb3,
        int* __restrict__ cursor, unsigned* __restrict__ pooled) {
    int idx = blockIdx.x * 256 + threadIdx.x;  // 0..8191

    if (idx < NB_BUCKETS) cursor[idx] = 0;
    for (int j = idx; j < N_GRAPHS * 64; j += 8192) pooled[j] = NEG_INF_MAPPED;

    // layer 1: K=128, F=32, NCF=4 (8192 elems)
    {
        const int K = 128, F = 32, NCF = 4;
        if (idx < K * 2 * F) {
            int frag = idx >> 9, within = idx & 511, lane = within >> 3, j = within & 7;
            int kf = frag / NCF, cf = frag % NCF;
            int k = kf * 32 + (lane >> 4) * 8 + j;
            int c = cf * 16 + (lane & 15);
            float v;
            if (c < F) {
                float s = gamma[c] * rsqrtf(var[c] + BN_EPS);
                v = Wt1[c * K + k] * s;
            } else {
                int cc = c - F;
                float s = gamma[cc] * rsqrtf(var[cc] + BN_EPS);
                v = (Wp1[cc * K + k] - Wt1[cc * K + k]) * s;
            }
            wsz1[idx] = __float2half(v);
        }
        if (idx < F) {
            float s = gamma[idx] * rsqrtf(var[idx] + BN_EPS);
            qb1[idx] = (bt1[idx] + bp1[idx]) * s + beta[idx] - mean[idx] * s;
        }
    }
    // layer 2: K=32, F=64, NCF=8 (4096 elems)
    {
        const int K = 32, F = 64, NCF = 8;
        if (idx < K * 2 * F) {
            int frag = idx >> 9, within = idx & 511, lane = within >> 3, j = within & 7;
            int kf = frag / NCF, cf = frag % NCF;
            int k = kf * 32 + (lane >> 4) * 8 + j;
            int c = cf * 16 + (lane & 15);
            float v = (c < F) ? Wt2[c * K + k]
                              : (Wp2[(c - F) * K + k] - Wt2[(c - F) * K + k]);
            wsz2[idx] = __float2half(v);
        }
        if (idx < F) qb2[idx] = bt2[idx] + bp2[idx];
    }
    // layer 3: K=64, F=64, NCF=8 (8192 elems)
    {
        const int K = 64, F = 64, NCF = 8;
        if (idx < K * 2 * F) {
            int frag = idx >> 9, within = idx & 511, lane = within >> 3, j = within & 7;
            int kf = frag / NCF, cf = frag % NCF;
            int k = kf * 32 + (lane >> 4) * 8 + j;
            int c = cf * 16 + (lane & 15);
            float v = (c < F) ? Wt3[c * K + k]
                              : (Wp3[(c - F) * K + k] - Wt3[(c - F) * K + k]);
            wsz3[idx] = __float2half(v);
        }
        if (idx < F) qb3[idx] = bt3[idx] + bp3[idx];
    }
}

// ---------- binned CSR build (padded buckets, no global scan) ----------
// bucket = dst >> 7. Packed edge: (src << 7) | (dst & 127).
__global__ __launch_bounds__(256) void scatter_kernel(const int* __restrict__ esrc,
                                                      const int* __restrict__ edst,
                                                      int* __restrict__ cursor,
                                                      unsigned* __restrict__ binned, int E) {
    __shared__ int hist[NB_BUCKETS];
    __shared__ int lbase[NB_BUCKETS];
    __shared__ unsigned pk[SCAT_CHUNK];
    __shared__ unsigned short bk[SCAT_CHUNK];
    int begE = blockIdx.x * SCAT_CHUNK;
    int endE = min(begE + SCAT_CHUNK, E);
    int n = endE - begE;
    for (int i = threadIdx.x; i < NB_BUCKETS; i += 256) hist[i] = 0;
    __syncthreads();
    for (int i = threadIdx.x; i < n; i += 256) {
        int d = edst[begE + i];
        int s = esrc[begE + i];
        int b = d >> 7;
        pk[i] = ((unsigned)s << 7) | (unsigned)(d & 127);
        bk[i] = (unsigned short)b;
        atomicAdd(&hist[b], 1);
    }
    __syncthreads();
    for (int i = threadIdx.x; i < NB_BUCKETS; i += 256) {
        int c = hist[i];
        lbase[i] = c ? (i * BUCKET_PAD + atomicAdd(&cursor[i], c)) : 0;
        hist[i] = 0;  // reuse as local cursor
    }
    __syncthreads();
    for (int i = threadIdx.x; i < n; i += 256) {
        int b = bk[i];
        int pos = lbase[b] + atomicAdd(&hist[b], 1);
        binned[pos] = pk[i];
    }
}

// one block per bucket: LDS-local CSR build, coalesced csr/beg/end writes.
__global__ __launch_bounds__(256) void bucket_build_kernel(const unsigned* __restrict__ binned,
                                                           const int* __restrict__ bcount,
                                                           int* __restrict__ begs,
                                                           int* __restrict__ ends,
                                                           int* __restrict__ csr) {
    __shared__ unsigned stage[BUCKET_CAP];
    __shared__ int srcLDS[BUCKET_CAP];
    __shared__ int cnt[BUCKET_NODES];
    __shared__ int sc[BUCKET_NODES];
    __shared__ int loff[BUCKET_NODES];

    int b = blockIdx.x;
    int ebeg = b * BUCKET_PAD;
    int ne = min(bcount[b], BUCKET_CAP);
    int tid = threadIdx.x;

    if (tid < BUCKET_NODES) cnt[tid] = 0;
    __syncthreads();
    for (int i = tid; i < ne; i += 256) {
        unsigned e = binned[ebeg + i];
        stage[i] = e;
        atomicAdd(&cnt[e & 127], 1);
    }
    __syncthreads();
    int v = (tid < BUCKET_NODES) ? cnt[tid] : 0;
    if (tid < BUCKET_NODES) sc[tid] = v;
    __syncthreads();
    for (int off = 1; off < BUCKET_NODES; off <<= 1) {
        int u = (tid < BUCKET_NODES && tid >= off) ? sc[tid - off] : 0;
        __syncthreads();
        if (tid < BUCKET_NODES) sc[tid] += u;
        __syncthreads();
    }
    if (tid < BUCKET_NODES) {
        loff[tid] = sc[tid] - v;
        cnt[tid] = 0;
    }
    __syncthreads();
    int gnode = b * BUCKET_NODES + tid;
    if (tid < BUCKET_NODES && gnode < N_NODES) {
        begs[gnode] = ebeg + loff[tid];
        ends[gnode] = ebeg + loff[tid] + v;
    }
    for (int i = tid; i < ne; i += 256) {
        unsigned e = stage[i];
        int ln = e & 127;
        int slot = loff[ln] + atomicAdd(&cnt[ln], 1);
        srcLDS[slot] = (int)(e >> 7);
    }
    __syncthreads();
    for (int i = tid; i < ne; i += 256) csr[ebeg + i] = srcLDS[i];
}

// ---------- x-fragment loaders ----------
// fp16 inputs are SLICE-MAJOR: x[(k>>3)][node][8]. kOff is always a multiple of 8.
template <int K>
static __device__ __forceinline__ f16x8 load_xfrag(const __half* __restrict__ x,
                                                   size_t node, int kOff) {
    return *reinterpret_cast<const f16x8*>(x + ((size_t)(kOff >> 3) * N_NODES + node) * 8);
}
// fp32 input (atom_feats) is node-major.
template <int K>
static __device__ __forceinline__ f16x8 load_xfrag(const float* __restrict__ x,
                                                   size_t node, int kOff) {
    const float* xr = x + node * K + kOff;
    float4 a0 = *reinterpret_cast<const float4*>(xr);
    float4 a1 = *reinterpret_cast<const float4*>(xr + 4);
    f16x8 a;
    a[0] = (_Float16)a0.x; a[1] = (_Float16)a0.y; a[2] = (_Float16)a0.z; a[3] = (_Float16)a0.w;
    a[4] = (_Float16)a1.x; a[5] = (_Float16)a1.y; a[6] = (_Float16)a1.z; a[7] = (_Float16)a1.w;
    return a;
}

// ---------- MFMA transform: [N x K] @ [K x 2F] -> t, q (both fp16, SLICE-MAJOR) ----------
// D = mfma(W_as_A, x_as_B): lane owns node = lane&15, channels c4..c4+3 per cfrag.
// Store 8 B to slice (c>>3), offset (c&7) in {0,4}.
template <int K, int F, typename IT>
__global__ __launch_bounds__(256) void transform_mfma(
        const IT* __restrict__ x, const __half* __restrict__ wsz,
        const float* __restrict__ qb,
        __half* __restrict__ t, __half* __restrict__ q) {
    constexpr int NKF = K / 32;
    constexpr int NCF = (2 * F) / 16;
    constexpr int NTILES = N_NODES / 16;  // 6250

    int lane = threadIdx.x & 63;
    int wid = blockIdx.x * 4 + (threadIdx.x >> 6);
    int nWaves = gridDim.x * 4;

    f16x8 wfrag[NKF][NCF];
#pragma unroll
    for (int kf = 0; kf < NKF; kf++)
#pragma unroll
        for (int cf = 0; cf < NCF; cf++)
            wfrag[kf][cf] = *reinterpret_cast<const f16x8*>(
                wsz + ((size_t)(kf * NCF + cf) * 64 + lane) * 8);

    int nrow = lane & 15;          // node within tile
    int kq8 = (lane >> 4) * 8;     // k offset within 32-k fragment
    int c4 = (lane >> 4) * 4;      // channel quad base within 16-c fragment

    for (int tile = wid; tile < NTILES; tile += nWaves) {
        size_t nodeBase = (size_t)tile * 16;

        f32x4 acc[NCF];
#pragma unroll
        for (int cf = 0; cf < NCF; cf++) acc[cf] = (f32x4){0.f, 0.f, 0.f, 0.f};

#pragma unroll
        for (int kf = 0; kf < NKF; kf++) {
            f16x8 a = load_xfrag<K>(x, nodeBase + nrow, kf * 32 + kq8);
#pragma unroll
            for (int cf = 0; cf < NCF; cf++)
                acc[cf] = __builtin_amdgcn_mfma_f32_16x16x32_f16(wfrag[kf][cf], a, acc[cf], 0, 0, 0);
        }

        size_t node = nodeBase + nrow;
#pragma unroll
        for (int cf = 0; cf < NCF; cf++) {
            int c = cf * 16 + c4;
            if (c < F) {
                f16x4 h;
#pragma unroll
                for (int r = 0; r < 4; r++) h[r] = (_Float16)acc[cf][r];
                *reinterpret_cast<f16x4*>(t + ((size_t)(c >> 3) * N_NODES + node) * 8 + (c & 7)) = h;
            } else {
                int cc = c - F;
                float4 qv = *reinterpret_cast<const float4*>(qb + cc);
                f16x4 h;
                h[0] = (_Float16)(acc[cf][0] + qv.x);
                h[1] = (_Float16)(acc[cf][1] + qv.y);
                h[2] = (_Float16)(acc[cf][2] + qv.z);
                h[3] = (_Float16)(acc[cf][3] + qv.w);
                *reinterpret_cast<f16x4*>(q + ((size_t)(cc >> 3) * N_NODES + node) * 8 + (cc & 7)) = h;
            }
        }
    }
}

// ---------- edge max + combine + ELU, XCD-sharded channel slices ----------
// slice = blockIdx%8 (mod NSLICE): all blocks of a slice land on one XCD (round-robin),
// so each XCD's q working set is N*16B = 1.6 MB -> L2-resident.
// One thread per (node, slice): gathers 16 B per edge.
template <int F>
__global__ __launch_bounds__(256) void edgemax_slice_kernel(
        const uint4* __restrict__ ts,   // [NSLICE][N]
        const uint4* __restrict__ qs,   // [NSLICE][N]
        const int* __restrict__ begs, const int* __restrict__ ends,
        const int* __restrict__ csr,
        uint4* __restrict__ outs, int N) {
    constexpr int NSLICE = F / 8;
    constexpr int REP = 8 / NSLICE;   // virtual slices per real slice
    int vs = blockIdx.x & 7;
    int slice = vs / REP;
    int sub = vs % REP;
    int chunk = (blockIdx.x >> 3) * REP + sub;
    int nd = chunk * 256 + threadIdx.x;
    if (nd >= N) return;

    const uint4* q = qs + (size_t)slice * N;
    int beg = begs[nd], end = ends[nd];

    uint4 mneg = {HALF2_NEG_INF, HALF2_NEG_INF, HALF2_NEG_INF, HALF2_NEG_INF};
    uint4 m0 = mneg, m1 = mneg, m2 = mneg, m3 = mneg;
    int i = beg;
    for (; i + 3 < end; i += 4) {
        int s0 = csr[i], s1 = csr[i + 1], s2 = csr[i + 2], s3 = csr[i + 3];
        m0 = pkmax4(m0, q[s0]);
        m1 = pkmax4(m1, q[s1]);
        m2 = pkmax4(m2, q[s2]);
        m3 = pkmax4(m3, q[s3]);
    }
    for (; i < end; i++) m0 = pkmax4(m0, q[csr[i]]);
    uint4 m = pkmax4(pkmax4(m0, m1), pkmax4(m2, m3));

    uint4 res;
    if (beg < end) {
        uint4 tv = ts[(size_t)slice * N + nd];
        unsigned* mp = &m.x;
        unsigned* tp = &tv.x;
        unsigned* rp = &res.x;
#pragma unroll
        for (int w = 0; w < 4; w++) {
            float2 mf = __half22float2(__builtin_bit_cast(__half2, mp[w]));
            float2 tf = __half22float2(__builtin_bit_cast(__half2, tp[w]));
            float rx = elu_f(tf.x + mf.x);
            float ry = elu_f(tf.y + mf.y);
            rp[w] = __builtin_bit_cast(unsigned, __floats2half2_rn(rx, ry));
        }
    } else {
        res = (uint4){0u, 0u, 0u, 0u};
    }
    outs[(size_t)slice * N + nd] = res;
}

// ---------- graph max pooling (fp16 slice-major input [8][N][8]) ----------
__global__ void pool_kernel(const __half* __restrict__ x, const int* __restrict__ gid,
                            unsigned* __restrict__ pooled, int N) {
    const int CHUNK = 64;
    int wave = (blockIdx.x * blockDim.x + threadIdx.x) >> 6;
    int lane = threadIdx.x & 63;
    int start = wave * CHUNK;
    if (start >= N) return;
    int end = min(start + CHUNK, N);
    const __half* base = x + (size_t)(lane >> 3) * N_NODES * 8 + (lane & 7);
    float m = -INFINITY;
    int cur = gid[start];
    for (int n = start; n < end; n++) {
        int g = gid[n];
        if (g != cur) {
            atomicMax(&pooled[cur * 64 + lane], fmap(m));
            cur = g;
            m = -INFINITY;
        }
        m = fmaxf(m, __half2float(base[(size_t)n * 8]));
    }
    atomicMax(&pooled[cur * 64 + lane], fmap(m));
}

// ---------- FC head + log_softmax, one block (64 threads) per graph ----------
__global__ __launch_bounds__(64) void fc_kernel(
        const unsigned* __restrict__ pooled,
        const float* __restrict__ Wf1, const float* __restrict__ bf1,
        const float* __restrict__ Wf2, const float* __restrict__ bf2,
        const float* __restrict__ Wf3, const float* __restrict__ bf3,
        float* __restrict__ out) {
    int g = blockIdx.x;
    int c = threadIdx.x;
    __shared__ float x0[64], h1[64], h2[32], h3[10];

    unsigned u = pooled[g * 64 + c];
    x0[c] = (u == NEG_INF_MAPPED) ? 0.f : funmap(u);
    __syncthreads();

    float a = bf1[c];
#pragma unroll 8
    for (int k = 0; k < 64; k++) a = fmaf(Wf1[c * 64 + k], x0[k], a);
    h1[c] = elu_f(a);
    __syncthreads();

    if (c < 32) {
        float a2 = bf2[c];
#pragma unroll 8
        for (int k = 0; k < 64; k++) a2 = fmaf(Wf2[c * 64 + k], h1[k], a2);
        h2[c] = elu_f(a2);
    }
    __syncthreads();

    if (c < 10) {
        float a3 = bf3[c];
#pragma unroll 8
        for (int k = 0; k < 32; k++) a3 = fmaf(Wf3[c * 32 + k], h2[k], a3);
        h3[c] = a3;
    }
    __syncthreads();

    if (c < 10) {
        float mx = h3[0];
#pragma unroll
        for (int j = 1; j < 10; j++) mx = fmaxf(mx, h3[j]);
        float s = 0.f;
#pragma unroll
        for (int j = 0; j < 10; j++) s += expf(h3[j] - mx);
        out[g * 10 + c] = h3[c] - mx - logf(s);
    }
}

// ---------- launch ----------
extern "C" void kernel_launch(void* const* d_in, const int* in_sizes, int n_in,
                              void* d_out, int out_size, void* d_ws, size_t ws_size,
                              hipStream_t stream) {
    const float* atom = (const float*)d_in[0];
    const int* esrc = (const int*)d_in[1];
    const int* edst = (const int*)d_in[2];
    const int* gid  = (const int*)d_in[3];
    const float* Wt1 = (const float*)d_in[4];
    const float* bt1 = (const float*)d_in[5];
    const float* Wp1 = (const float*)d_in[6];
    const float* bp1 = (const float*)d_in[7];
    const float* bng = (const float*)d_in[8];
    const float* bnb = (const float*)d_in[9];
    const float* bnm = (const float*)d_in[10];
    const float* bnv = (const float*)d_in[11];
    const float* Wt2 = (const float*)d_in[12];
    const float* bt2 = (const float*)d_in[13];
    const float* Wp2 = (const float*)d_in[14];
    const float* bp2 = (const float*)d_in[15];
    const float* Wt3 = (const float*)d_in[16];
    const float* bt3 = (const float*)d_in[17];
    const float* Wp3 = (const float*)d_in[18];
    const float* bp3 = (const float*)d_in[19];
    const float* Wf1 = (const float*)d_in[20];
    const float* bf1 = (const float*)d_in[21];
    const float* Wf2 = (const float*)d_in[22];
    const float* bf2 = (const float*)d_in[23];
    const float* Wf3 = (const float*)d_in[24];
    const float* bf3 = (const float*)d_in[25];

    // workspace carve-up
    char* p = (char*)d_ws;
    auto alloc = [&](size_t bytes) -> void* {
        void* r = (void*)p;
        p += (bytes + 255) & ~(size_t)255;
        return r;
    };
    int* begs        = (int*)alloc(sizeof(int) * N_NODES);
    int* ends        = (int*)alloc(sizeof(int) * N_NODES);
    int* cursor      = (int*)alloc(sizeof(int) * NB_BUCKETS);
    unsigned* binned = (unsigned*)alloc(sizeof(unsigned) * NB_BUCKETS * BUCKET_PAD);
    int* csr         = (int*)alloc(sizeof(int) * NB_BUCKETS * BUCKET_PAD);
    __half* wsz1 = (__half*)alloc(sizeof(__half) * 128 * 64);
    __half* wsz2 = (__half*)alloc(sizeof(__half) * 32 * 128);
    __half* wsz3 = (__half*)alloc(sizeof(__half) * 64 * 128);
    float* qb1   = (float*)alloc(sizeof(float) * 32);
    float* qb2   = (float*)alloc(sizeof(float) * 64);
    float* qb3   = (float*)alloc(sizeof(float) * 64);
    __half* tbuf = (__half*)alloc(sizeof(__half) * (size_t)N_NODES * 64);
    __half* qbuf = (__half*)alloc(sizeof(__half) * (size_t)N_NODES * 64);
    __half* xh   = (__half*)alloc(sizeof(__half) * (size_t)N_NODES * 64);
    unsigned* pooled = (unsigned*)alloc(sizeof(unsigned) * N_GRAPHS * 64);

    const int NCHUNK = (N_NODES + 255) / 256;  // 391

    // prep (also zeroes cursor + inits pooled) + CSR build
    prep_kernel<<<32, 256, 0, stream>>>(Wt1, bt1, Wp1, bp1, bng, bnb, bnm, bnv,
                                        Wt2, bt2, Wp2, bp2, Wt3, bt3, Wp3, bp3,
                                        wsz1, qb1, wsz2, qb2, wsz3, qb3, cursor, pooled);
    scatter_kernel<<<(N_EDGES + SCAT_CHUNK - 1) / SCAT_CHUNK, 256, 0, stream>>>(
        esrc, edst, cursor, binned, N_EDGES);
    bucket_build_kernel<<<NB_BUCKETS, 256, 0, stream>>>(binned, cursor, begs, ends, csr);

    // layer 1: 128 -> 32 (BN folded), fp32 input; NSLICE=4 -> REP=2
    transform_mfma<128, 32, float><<<782, 256, 0, stream>>>(atom, wsz1, qb1, tbuf, qbuf);
    edgemax_slice_kernel<32><<<8 * ((NCHUNK + 1) / 2), 256, 0, stream>>>(
        (const uint4*)tbuf, (const uint4*)qbuf, begs, ends, csr, (uint4*)xh, N_NODES);

    // layer 2: 32 -> 64, fp16 slice-major input; NSLICE=8 -> REP=1
    transform_mfma<32, 64, __half><<<782, 256, 0, stream>>>(xh, wsz2, qb2, tbuf, qbuf);
    edgemax_slice_kernel<64><<<8 * NCHUNK, 256, 0, stream>>>(
        (const uint4*)tbuf, (const uint4*)qbuf, begs, ends, csr, (uint4*)xh, N_NODES);

    // layer 3: 64 -> 64, fp16 slice-major input
    transform_mfma<64, 64, __half><<<782, 256, 0, stream>>>(xh, wsz3, qb3, tbuf, qbuf);
    edgemax_slice_kernel<64><<<8 * NCHUNK, 256, 0, stream>>>(
        (const uint4*)tbuf, (const uint4*)qbuf, begs, ends, csr, (uint4*)xh, N_NODES);

    // graph pooling (slice-major input)
    {
        int waves = (N_NODES + 63) / 64;
        int blocks = (waves + 3) / 4;
        pool_kernel<<<blocks, 256, 0, stream>>>(xh, gid, pooled, N_NODES);
    }

    // FC head
    fc_kernel<<<N_GRAPHS, 64, 0, stream>>>(pooled, Wf1, bf1, Wf2, bf2, Wf3, bf3, (float*)d_out);
}

// Round 10
// 190.858 us; speedup vs baseline: 1.1544x; 1.1544x over previous
//
#include <hip/hip_runtime.h>
#include <hip/hip_fp16.h>
#include <math.h>

#define N_NODES 100000
#define N_EDGES 1000000
#define N_GRAPHS 1024
#define BN_EPS 1e-5f

#define BUCKET_NODES 128
#define NB_BUCKETS ((N_NODES + BUCKET_NODES - 1) / BUCKET_NODES)  // 782
#define BUCKET_PAD 2048   // fixed per-bucket slot; counts ~Poisson(1280), >20 sigma margin
#define BUCKET_CAP 3072
#define SCAT_CHUNK 2048
#define N_RANKS (NB_BUCKETS * BUCKET_NODES)  // 100096

typedef __attribute__((__ext_vector_type__(8))) _Float16 f16x8;
typedef __attribute__((__ext_vector_type__(4))) _Float16 f16x4;
typedef __attribute__((__ext_vector_type__(4))) float f32x4;

// ---------- helpers ----------
static __device__ __forceinline__ float elu_f(float v) {
    return v > 0.f ? v : expm1f(v);
}

// packed fp16 max (2 halves) — gfx950 v_pk_max_f16
static __device__ __forceinline__ unsigned pkmax(unsigned a, unsigned b) {
    unsigned r;
    asm("v_pk_max_f16 %0, %1, %2" : "=v"(r) : "v"(a), "v"(b));
    return r;
}
#define HALF2_NEG_INF 0xFC00FC00u

static __device__ __forceinline__ uint4 pkmax4(uint4 a, uint4 b) {
    uint4 r;
    r.x = pkmax(a.x, b.x);
    r.y = pkmax(a.y, b.y);
    r.z = pkmax(a.z, b.z);
    r.w = pkmax(a.w, b.w);
    return r;
}

// monotone float -> uint mapping (order-preserving) for atomicMax on floats
static __device__ __forceinline__ unsigned fmap(float f) {
    unsigned u = __float_as_uint(f);
    return (u & 0x80000000u) ? ~u : (u | 0x80000000u);
}
static __device__ __forceinline__ float funmap(unsigned u) {
    unsigned b = (u & 0x80000000u) ? (u & 0x7FFFFFFFu) : ~u;
    return __uint_as_float(b);
}
#define NEG_INF_MAPPED 0x007FFFFFu  // fmap(-inf)

// ---------- prep: weight blobs + biases + cursor/pooled/ord init ----------
__global__ __launch_bounds__(256) void prep_kernel(
        const float* __restrict__ Wt1, const float* __restrict__ bt1,
        const float* __restrict__ Wp1, const float* __restrict__ bp1,
        const float* __restrict__ gamma, const float* __restrict__ beta,
        const float* __restrict__ mean,  const float* __restrict__ var,
        const float* __restrict__ Wt2, const float* __restrict__ bt2,
        const float* __restrict__ Wp2, const float* __restrict__ bp2,
        const float* __restrict__ Wt3, const float* __restrict__ bt3,
        const float* __restrict__ Wp3, const float* __restrict__ bp3,
        __half* __restrict__ wsz1, float* __restrict__ qb1,
        __half* __restrict__ wsz2, float* __restrict__ qb2,
        __half* __restrict__ wsz3, float* __restrict__ qb3,
        int* __restrict__ cursor, unsigned* __restrict__ pooled,
        int* __restrict__ ord) {
    int idx = blockIdx.x * 256 + threadIdx.x;  // 0..8191

    if (idx < NB_BUCKETS) cursor[idx] = 0;
    for (int j = idx; j < N_GRAPHS * 64; j += 8192) pooled[j] = NEG_INF_MAPPED;
    for (int j = idx; j < N_RANKS; j += 8192) ord[j] = N_NODES;  // sentinel init (race-free: separate dispatch)

    // layer 1: K=128, F=32, NCF=4 (8192 elems)
    {
        const int K = 128, F = 32, NCF = 4;
        if (idx < K * 2 * F) {
            int frag = idx >> 9, within = idx & 511, lane = within >> 3, j = within & 7;
            int kf = frag / NCF, cf = frag % NCF;
            int k = kf * 32 + (lane >> 4) * 8 + j;
            int c = cf * 16 + (lane & 15);
            float v;
            if (c < F) {
                float s = gamma[c] * rsqrtf(var[c] + BN_EPS);
                v = Wt1[c * K + k] * s;
            } else {
                int cc = c - F;
                float s = gamma[cc] * rsqrtf(var[cc] + BN_EPS);
                v = (Wp1[cc * K + k] - Wt1[cc * K + k]) * s;
            }
            wsz1[idx] = __float2half(v);
        }
        if (idx < F) {
            float s = gamma[idx] * rsqrtf(var[idx] + BN_EPS);
            qb1[idx] = (bt1[idx] + bp1[idx]) * s + beta[idx] - mean[idx] * s;
        }
    }
    // layer 2: K=32, F=64, NCF=8 (4096 elems)
    {
        const int K = 32, F = 64, NCF = 8;
        if (idx < K * 2 * F) {
            int frag = idx >> 9, within = idx & 511, lane = within >> 3, j = within & 7;
            int kf = frag / NCF, cf = frag % NCF;
            int k = kf * 32 + (lane >> 4) * 8 + j;
            int c = cf * 16 + (lane & 15);
            float v = (c < F) ? Wt2[c * K + k]
                              : (Wp2[(c - F) * K + k] - Wt2[(c - F) * K + k]);
            wsz2[idx] = __float2half(v);
        }
        if (idx < F) qb2[idx] = bt2[idx] + bp2[idx];
    }
    // layer 3: K=64, F=64, NCF=8 (8192 elems)
    {
        const int K = 64, F = 64, NCF = 8;
        if (idx < K * 2 * F) {
            int frag = idx >> 9, within = idx & 511, lane = within >> 3, j = within & 7;
            int kf = frag / NCF, cf = frag % NCF;
            int k = kf * 32 + (lane >> 4) * 8 + j;
            int c = cf * 16 + (lane & 15);
            float v = (c < F) ? Wt3[c * K + k]
                              : (Wp3[(c - F) * K + k] - Wt3[(c - F) * K + k]);
            wsz3[idx] = __float2half(v);
        }
        if (idx < F) qb3[idx] = bt3[idx] + bp3[idx];
    }
}

// ---------- binned CSR build (padded buckets, no global scan) ----------
// bucket = dst >> 7. Packed edge: (src << 7) | (dst & 127).
__global__ __launch_bounds__(256) void scatter_kernel(const int* __restrict__ esrc,
                                                      const int* __restrict__ edst,
                                                      int* __restrict__ cursor,
                                                      unsigned* __restrict__ binned, int E) {
    __shared__ int hist[NB_BUCKETS];
    __shared__ int lbase[NB_BUCKETS];
    __shared__ unsigned pk[SCAT_CHUNK];
    __shared__ unsigned short bk[SCAT_CHUNK];
    int begE = blockIdx.x * SCAT_CHUNK;
    int endE = min(begE + SCAT_CHUNK, E);
    int n = endE - begE;
    for (int i = threadIdx.x; i < NB_BUCKETS; i += 256) hist[i] = 0;
    __syncthreads();
    for (int i = threadIdx.x; i < n; i += 256) {
        int d = edst[begE + i];
        int s = esrc[begE + i];
        int b = d >> 7;
        pk[i] = ((unsigned)s << 7) | (unsigned)(d & 127);
        bk[i] = (unsigned short)b;
        atomicAdd(&hist[b], 1);
    }
    __syncthreads();
    for (int i = threadIdx.x; i < NB_BUCKETS; i += 256) {
        int c = hist[i];
        lbase[i] = c ? (i * BUCKET_PAD + atomicAdd(&cursor[i], c)) : 0;
        hist[i] = 0;  // reuse as local cursor
    }
    __syncthreads();
    for (int i = threadIdx.x; i < n; i += 256) {
        int b = bk[i];
        int pos = lbase[b] + atomicAdd(&hist[b], 1);
        binned[pos] = pk[i];
    }
}

// one block per bucket: LDS-local CSR build + degree-sorted node order.
// ord rank slots are written AT MOST ONCE per kernel (sentinels pre-set by prep).
__global__ __launch_bounds__(256) void bucket_build_kernel(const unsigned* __restrict__ binned,
                                                           const int* __restrict__ bcount,
                                                           int* __restrict__ begs,
                                                           int* __restrict__ ends,
                                                           int* __restrict__ csr,
                                                           int* __restrict__ ord) {
    __shared__ unsigned stage[BUCKET_CAP];
    __shared__ int srcLDS[BUCKET_CAP];
    __shared__ int cnt[BUCKET_NODES];
    __shared__ int sc[BUCKET_NODES];
    __shared__ int loff[BUCKET_NODES];
    __shared__ int dhist[64];
    __shared__ int dcur[64];

    int b = blockIdx.x;
    int ebeg = b * BUCKET_PAD;
    int ne = min(bcount[b], BUCKET_CAP);
    int tid = threadIdx.x;

    if (tid < BUCKET_NODES) cnt[tid] = 0;
    if (tid < 64) { dhist[tid] = 0; dcur[tid] = 0; }
    __syncthreads();
    for (int i = tid; i < ne; i += 256) {
        unsigned e = binned[ebeg + i];
        stage[i] = e;
        atomicAdd(&cnt[e & 127], 1);
    }
    __syncthreads();
    int v = (tid < BUCKET_NODES) ? cnt[tid] : 0;
    if (tid < BUCKET_NODES) sc[tid] = v;
    __syncthreads();
    for (int off = 1; off < BUCKET_NODES; off <<= 1) {
        int u = (tid < BUCKET_NODES && tid >= off) ? sc[tid - off] : 0;
        __syncthreads();
        if (tid < BUCKET_NODES) sc[tid] += u;
        __syncthreads();
    }
    if (tid < BUCKET_NODES) {
        loff[tid] = sc[tid] - v;
        cnt[tid] = 0;
    }
    __syncthreads();
    int gnode = b * BUCKET_NODES + tid;
    bool validNode = (tid < BUCKET_NODES) && (gnode < N_NODES);
    if (validNode) {
        begs[gnode] = ebeg + loff[tid];
        ends[gnode] = ebeg + loff[tid] + v;
    }
    // degree histogram (64 bins, clamped)
    int bin = min(v, 63);
    if (validNode) atomicAdd(&dhist[bin], 1);
    __syncthreads();
    if (tid == 0) {
        int run = 0;
        for (int i = 0; i < 64; i++) { int c = dhist[i]; dhist[i] = run; run += c; }
    }
    __syncthreads();
    if (validNode) {
        int r = dhist[bin] + atomicAdd(&dcur[bin], 1);
        ord[b * BUCKET_NODES + r] = gnode;   // each slot written at most once
    }
    // local scatter
    for (int i = tid; i < ne; i += 256) {
        unsigned e = stage[i];
        int ln = e & 127;
        int slot = loff[ln] + atomicAdd(&cnt[ln], 1);
        srcLDS[slot] = (int)(e >> 7);
    }
    __syncthreads();
    for (int i = tid; i < ne; i += 256) csr[ebeg + i] = srcLDS[i];
}

// ---------- x-fragment loaders (node-major) ----------
template <int K>
static __device__ __forceinline__ f16x8 load_xfrag(const __half* __restrict__ x,
                                                   size_t node, int kOff) {
    return *reinterpret_cast<const f16x8*>(x + node * K + kOff);
}
template <int K>
static __device__ __forceinline__ f16x8 load_xfrag(const float* __restrict__ x,
                                                   size_t node, int kOff) {
    const float* xr = x + node * K + kOff;
    float4 a0 = *reinterpret_cast<const float4*>(xr);
    float4 a1 = *reinterpret_cast<const float4*>(xr + 4);
    f16x8 a;
    a[0] = (_Float16)a0.x; a[1] = (_Float16)a0.y; a[2] = (_Float16)a0.z; a[3] = (_Float16)a0.w;
    a[4] = (_Float16)a1.x; a[5] = (_Float16)a1.y; a[6] = (_Float16)a1.z; a[7] = (_Float16)a1.w;
    return a;
}

// ---------- MFMA transform: [N x K] @ [K x 2F] -> t (fp16), q+qbias (fp16), node-major ----------
template <int K, int F, typename IT>
__global__ __launch_bounds__(256) void transform_mfma(
        const IT* __restrict__ x, const __half* __restrict__ wsz,
        const float* __restrict__ qb,
        __half* __restrict__ t, __half* __restrict__ q) {
    constexpr int NKF = K / 32;
    constexpr int NCF = (2 * F) / 16;
    constexpr int NTILES = N_NODES / 16;  // 6250

    int lane = threadIdx.x & 63;
    int wid = blockIdx.x * 4 + (threadIdx.x >> 6);
    int nWaves = gridDim.x * 4;

    f16x8 wfrag[NKF][NCF];
#pragma unroll
    for (int kf = 0; kf < NKF; kf++)
#pragma unroll
        for (int cf = 0; cf < NCF; cf++)
            wfrag[kf][cf] = *reinterpret_cast<const f16x8*>(
                wsz + ((size_t)(kf * NCF + cf) * 64 + lane) * 8);

    int nrow = lane & 15;          // node within tile
    int kq8 = (lane >> 4) * 8;     // k offset within 32-k fragment
    int c4 = (lane >> 4) * 4;      // channel quad base within 16-c fragment

    for (int tile = wid; tile < NTILES; tile += nWaves) {
        size_t nodeBase = (size_t)tile * 16;

        f32x4 acc[NCF];
#pragma unroll
        for (int cf = 0; cf < NCF; cf++) acc[cf] = (f32x4){0.f, 0.f, 0.f, 0.f};

#pragma unroll
        for (int kf = 0; kf < NKF; kf++) {
            f16x8 a = load_xfrag<K>(x, nodeBase + nrow, kf * 32 + kq8);
#pragma unroll
            for (int cf = 0; cf < NCF; cf++)
                acc[cf] = __builtin_amdgcn_mfma_f32_16x16x32_f16(wfrag[kf][cf], a, acc[cf], 0, 0, 0);
        }

        size_t node = nodeBase + nrow;
#pragma unroll
        for (int cf = 0; cf < NCF; cf++) {
            int c = cf * 16 + c4;
            if (c < F) {
                f16x4 h;
#pragma unroll
                for (int r = 0; r < 4; r++) h[r] = (_Float16)acc[cf][r];
                *reinterpret_cast<f16x4*>(t + node * F + c) = h;
            } else {
                int cc = c - F;
                float4 qv = *reinterpret_cast<const float4*>(qb + cc);
                f16x4 h;
                h[0] = (_Float16)(acc[cf][0] + qv.x);
                h[1] = (_Float16)(acc[cf][1] + qv.y);
                h[2] = (_Float16)(acc[cf][2] + qv.z);
                h[3] = (_Float16)(acc[cf][3] + qv.w);
                *reinterpret_cast<f16x4*>(q + node * F + cc) = h;
            }
        }
    }
}

// ---------- edge max + combine + ELU (uint4 gathers, 4x unroll, degree-sorted order) ----------
template <int F>
__global__ __launch_bounds__(256) void edgemax_kernel(
        const uint4* __restrict__ t16, const uint4* __restrict__ q16,  // [N][F/8]
        const int* __restrict__ begs, const int* __restrict__ ends,
        const int* __restrict__ csr, const int* __restrict__ ord,
        uint4* __restrict__ out, int N) {
    constexpr int NPG = F / 8;      // threads per node (8 channels each)
    constexpr int G = 256 / NPG;    // nodes per block
    int g = threadIdx.x / NPG;
    int cp = threadIdx.x % NPG;
    int rank = blockIdx.x * G + g;
    int nd = ord[rank];
    if (nd >= N) return;
    int beg = begs[nd], end = ends[nd];

    uint4 mneg = {HALF2_NEG_INF, HALF2_NEG_INF, HALF2_NEG_INF, HALF2_NEG_INF};
    uint4 m0 = mneg, m1 = mneg, m2 = mneg, m3 = mneg;
    int i = beg;
    for (; i + 3 < end; i += 4) {
        int s0 = csr[i], s1 = csr[i + 1], s2 = csr[i + 2], s3 = csr[i + 3];
        m0 = pkmax4(m0, q16[(size_t)s0 * NPG + cp]);
        m1 = pkmax4(m1, q16[(size_t)s1 * NPG + cp]);
        m2 = pkmax4(m2, q16[(size_t)s2 * NPG + cp]);
        m3 = pkmax4(m3, q16[(size_t)s3 * NPG + cp]);
    }
    for (; i < end; i++) {
        m0 = pkmax4(m0, q16[(size_t)csr[i] * NPG + cp]);
    }
    uint4 m = pkmax4(pkmax4(m0, m1), pkmax4(m2, m3));

    uint4 res;
    if (beg < end) {
        uint4 tv = t16[(size_t)nd * NPG + cp];
        unsigned* mp = &m.x;
        unsigned* tp = &tv.x;
        unsigned* rp = &res.x;
#pragma unroll
        for (int w = 0; w < 4; w++) {
            float2 mf = __half22float2(__builtin_bit_cast(__half2, mp[w]));
            float2 tf = __half22float2(__builtin_bit_cast(__half2, tp[w]));
            float rx = elu_f(tf.x + mf.x);
            float ry = elu_f(tf.y + mf.y);
            rp[w] = __builtin_bit_cast(unsigned, __floats2half2_rn(rx, ry));
        }
    } else {
        res = (uint4){0u, 0u, 0u, 0u};
    }
    out[(size_t)nd * NPG + cp] = res;
}

// ---------- graph max pooling (fp16 node-major input) ----------
__global__ void pool_kernel(const __half* __restrict__ x, const int* __restrict__ gid,
                            unsigned* __restrict__ pooled, int N) {
    const int CHUNK = 64;
    int wave = (blockIdx.x * blockDim.x + threadIdx.x) >> 6;
    int lane = threadIdx.x & 63;
    int start = wave * CHUNK;
    if (start >= N) return;
    int end = min(start + CHUNK, N);
    float m = -INFINITY;
    int cur = gid[start];
    for (int n = start; n < end; n++) {
        int g = gid[n];
        if (g != cur) {
            atomicMax(&pooled[cur * 64 + lane], fmap(m));
            cur = g;
            m = -INFINITY;
        }
        m = fmaxf(m, __half2float(x[(size_t)n * 64 + lane]));
    }
    atomicMax(&pooled[cur * 64 + lane], fmap(m));
}

// ---------- FC head + log_softmax, one block (64 threads) per graph ----------
__global__ __launch_bounds__(64) void fc_kernel(
        const unsigned* __restrict__ pooled,
        const float* __restrict__ Wf1, const float* __restrict__ bf1,
        const float* __restrict__ Wf2, const float* __restrict__ bf2,
        const float* __restrict__ Wf3, const float* __restrict__ bf3,
        float* __restrict__ out) {
    int g = blockIdx.x;
    int c = threadIdx.x;
    __shared__ float x0[64], h1[64], h2[32], h3[10];

    unsigned u = pooled[g * 64 + c];
    x0[c] = (u == NEG_INF_MAPPED) ? 0.f : funmap(u);
    __syncthreads();

    float a = bf1[c];
#pragma unroll 8
    for (int k = 0; k < 64; k++) a = fmaf(Wf1[c * 64 + k], x0[k], a);
    h1[c] = elu_f(a);
    __syncthreads();

    if (c < 32) {
        float a2 = bf2[c];
#pragma unroll 8
        for (int k = 0; k < 64; k++) a2 = fmaf(Wf2[c * 64 + k], h1[k], a2);
        h2[c] = elu_f(a2);
    }
    __syncthreads();

    if (c < 10) {
        float a3 = bf3[c];
#pragma unroll 8
        for (int k = 0; k < 32; k++) a3 = fmaf(Wf3[c * 32 + k], h2[k], a3);
        h3[c] = a3;
    }
    __syncthreads();

    if (c < 10) {
        float mx = h3[0];
#pragma unroll
        for (int j = 1; j < 10; j++) mx = fmaxf(mx, h3[j]);
        float s = 0.f;
#pragma unroll
        for (int j = 0; j < 10; j++) s += expf(h3[j] - mx);
        out[g * 10 + c] = h3[c] - mx - logf(s);
    }
}

// ---------- launch ----------
extern "C" void kernel_launch(void* const* d_in, const int* in_sizes, int n_in,
                              void* d_out, int out_size, void* d_ws, size_t ws_size,
                              hipStream_t stream) {
    const float* atom = (const float*)d_in[0];
    const int* esrc = (const int*)d_in[1];
    const int* edst = (const int*)d_in[2];
    const int* gid  = (const int*)d_in[3];
    const float* Wt1 = (const float*)d_in[4];
    const float* bt1 = (const float*)d_in[5];
    const float* Wp1 = (const float*)d_in[6];
    const float* bp1 = (const float*)d_in[7];
    const float* bng = (const float*)d_in[8];
    const float* bnb = (const float*)d_in[9];
    const float* bnm = (const float*)d_in[10];
    const float* bnv = (const float*)d_in[11];
    const float* Wt2 = (const float*)d_in[12];
    const float* bt2 = (const float*)d_in[13];
    const float* Wp2 = (const float*)d_in[14];
    const float* bp2 = (const float*)d_in[15];
    const float* Wt3 = (const float*)d_in[16];
    const float* bt3 = (const float*)d_in[17];
    const float* Wp3 = (const float*)d_in[18];
    const float* bp3 = (const float*)d_in[19];
    const float* Wf1 = (const float*)d_in[20];
    const float* bf1 = (const float*)d_in[21];
    const float* Wf2 = (const float*)d_in[22];
    const float* bf2 = (const float*)d_in[23];
    const float* Wf3 = (const float*)d_in[24];
    const float* bf3 = (const float*)d_in[25];

    // workspace carve-up
    char* p = (char*)d_ws;
    auto alloc = [&](size_t bytes) -> void* {
        void* r = (void*)p;
        p += (bytes + 255) & ~(size_t)255;
        return r;
    };
    int* begs        = (int*)alloc(sizeof(int) * N_NODES);
    int* ends        = (int*)alloc(sizeof(int) * N_NODES);
    int* ord         = (int*)alloc(sizeof(int) * N_RANKS);
    int* cursor      = (int*)alloc(sizeof(int) * NB_BUCKETS);
    unsigned* binned = (unsigned*)alloc(sizeof(unsigned) * NB_BUCKETS * BUCKET_PAD);
    int* csr         = (int*)alloc(sizeof(int) * NB_BUCKETS * BUCKET_PAD);
    __half* wsz1 = (__half*)alloc(sizeof(__half) * 128 * 64);
    __half* wsz2 = (__half*)alloc(sizeof(__half) * 32 * 128);
    __half* wsz3 = (__half*)alloc(sizeof(__half) * 64 * 128);
    float* qb1   = (float*)alloc(sizeof(float) * 32);
    float* qb2   = (float*)alloc(sizeof(float) * 64);
    float* qb3   = (float*)alloc(sizeof(float) * 64);
    __half* tbuf = (__half*)alloc(sizeof(__half) * (size_t)N_NODES * 64);
    __half* qbuf = (__half*)alloc(sizeof(__half) * (size_t)N_NODES * 64);
    __half* xh   = (__half*)alloc(sizeof(__half) * (size_t)N_NODES * 64);
    unsigned* pooled = (unsigned*)alloc(sizeof(unsigned) * N_GRAPHS * 64);

    // prep (zeroes cursor, inits pooled + ord sentinels) + CSR build
    prep_kernel<<<32, 256, 0, stream>>>(Wt1, bt1, Wp1, bp1, bng, bnb, bnm, bnv,
                                        Wt2, bt2, Wp2, bp2, Wt3, bt3, Wp3, bp3,
                                        wsz1, qb1, wsz2, qb2, wsz3, qb3, cursor, pooled, ord);
    scatter_kernel<<<(N_EDGES + SCAT_CHUNK - 1) / SCAT_CHUNK, 256, 0, stream>>>(
        esrc, edst, cursor, binned, N_EDGES);
    bucket_build_kernel<<<NB_BUCKETS, 256, 0, stream>>>(binned, cursor, begs, ends, csr, ord);

    // layer 1: 128 -> 32 (BN folded), fp32 input; NPG=4 -> G=64
    transform_mfma<128, 32, float><<<782, 256, 0, stream>>>(atom, wsz1, qb1, tbuf, qbuf);
    edgemax_kernel<32><<<N_RANKS / 64, 256, 0, stream>>>(
        (const uint4*)tbuf, (const uint4*)qbuf, begs, ends, csr, ord, (uint4*)xh, N_NODES);

    // layer 2: 32 -> 64, fp16 input; NPG=8 -> G=32
    transform_mfma<32, 64, __half><<<782, 256, 0, stream>>>(xh, wsz2, qb2, tbuf, qbuf);
    edgemax_kernel<64><<<N_RANKS / 32, 256, 0, stream>>>(
        (const uint4*)tbuf, (const uint4*)qbuf, begs, ends, csr, ord, (uint4*)xh, N_NODES);

    // layer 3: 64 -> 64, fp16 input
    transform_mfma<64, 64, __half><<<782, 256, 0, stream>>>(xh, wsz3, qb3, tbuf, qbuf);
    edgemax_kernel<64><<<N_RANKS / 32, 256, 0, stream>>>(
        (const uint4*)tbuf, (const uint4*)qbuf, begs, ends, csr, ord, (uint4*)xh, N_NODES);

    // graph pooling
    {
        int waves = (N_NODES + 63) / 64;
        int blocks = (waves + 3) / 4;
        pool_kernel<<<blocks, 256, 0, stream>>>(xh, gid, pooled, N_NODES);
    }

    // FC head
    fc_kernel<<<N_GRAPHS, 64, 0, stream>>>(pooled, Wf1, bf1, Wf2, bf2, Wf3, bf3, (float*)d_out);
}

// Round 11
// 178.250 us; speedup vs baseline: 1.2360x; 1.0707x over previous
//
#include <hip/hip_runtime.h>
#include <hip/hip_fp16.h>
#include <math.h>

#define N_NODES 100000
#define N_EDGES 1000000
#define N_GRAPHS 1024
#define BN_EPS 1e-5f

#define BUCKET_NODES 128
#define NB_BUCKETS ((N_NODES + BUCKET_NODES - 1) / BUCKET_NODES)  // 782
#define BUCKET_PAD 2048   // fixed per-bucket slot; counts ~Poisson(1280), >20 sigma margin
#define BUCKET_CAP 3072
#define SCAT_CHUNK 2048

typedef __attribute__((__ext_vector_type__(8))) _Float16 f16x8;
typedef __attribute__((__ext_vector_type__(4))) _Float16 f16x4;
typedef __attribute__((__ext_vector_type__(4))) float f32x4;

// ---------- helpers ----------
static __device__ __forceinline__ float elu_f(float v) {
    return v > 0.f ? v : expm1f(v);
}

// packed fp16 max (2 halves) — gfx950 v_pk_max_f16
static __device__ __forceinline__ unsigned pkmax(unsigned a, unsigned b) {
    unsigned r;
    asm("v_pk_max_f16 %0, %1, %2" : "=v"(r) : "v"(a), "v"(b));
    return r;
}
#define HALF2_NEG_INF 0xFC00FC00u

static __device__ __forceinline__ uint4 pkmax4(uint4 a, uint4 b) {
    uint4 r;
    r.x = pkmax(a.x, b.x);
    r.y = pkmax(a.y, b.y);
    r.z = pkmax(a.z, b.z);
    r.w = pkmax(a.w, b.w);
    return r;
}

// monotone float -> uint mapping (order-preserving) for atomicMax on floats
static __device__ __forceinline__ unsigned fmap(float f) {
    unsigned u = __float_as_uint(f);
    return (u & 0x80000000u) ? ~u : (u | 0x80000000u);
}
static __device__ __forceinline__ float funmap(unsigned u) {
    unsigned b = (u & 0x80000000u) ? (u & 0x7FFFFFFFu) : ~u;
    return __uint_as_float(b);
}
#define NEG_INF_MAPPED 0x007FFFFFu  // fmap(-inf)

// ---------- prep: fragment-order fp16 weight blobs + biases + cursor/pooled init ----------
__global__ __launch_bounds__(256) void prep_kernel(
        const float* __restrict__ Wt1, const float* __restrict__ bt1,
        const float* __restrict__ Wp1, const float* __restrict__ bp1,
        const float* __restrict__ gamma, const float* __restrict__ beta,
        const float* __restrict__ mean,  const float* __restrict__ var,
        const float* __restrict__ Wt2, const float* __restrict__ bt2,
        const float* __restrict__ Wp2, const float* __restrict__ bp2,
        const float* __restrict__ Wt3, const float* __restrict__ bt3,
        const float* __restrict__ Wp3, const float* __restrict__ bp3,
        __half* __restrict__ wsz1, float* __restrict__ qb1,
        __half* __restrict__ wsz2, float* __restrict__ qb2,
        __half* __restrict__ wsz3, float* __restrict__ qb3,
        int* __restrict__ cursor, unsigned* __restrict__ pooled) {
    int idx = blockIdx.x * 256 + threadIdx.x;  // 0..8191

    if (idx < NB_BUCKETS) cursor[idx] = 0;
    for (int j = idx; j < N_GRAPHS * 64; j += 8192) pooled[j] = NEG_INF_MAPPED;

    // layer 1: K=128, F=32, NCF=4 (8192 elems)
    {
        const int K = 128, F = 32, NCF = 4;
        if (idx < K * 2 * F) {
            int frag = idx >> 9, within = idx & 511, lane = within >> 3, j = within & 7;
            int kf = frag / NCF, cf = frag % NCF;
            int k = kf * 32 + (lane >> 4) * 8 + j;
            int c = cf * 16 + (lane & 15);
            float v;
            if (c < F) {
                float s = gamma[c] * rsqrtf(var[c] + BN_EPS);
                v = Wt1[c * K + k] * s;
            } else {
                int cc = c - F;
                float s = gamma[cc] * rsqrtf(var[cc] + BN_EPS);
                v = (Wp1[cc * K + k] - Wt1[cc * K + k]) * s;
            }
            wsz1[idx] = __float2half(v);
        }
        if (idx < F) {
            float s = gamma[idx] * rsqrtf(var[idx] + BN_EPS);
            qb1[idx] = (bt1[idx] + bp1[idx]) * s + beta[idx] - mean[idx] * s;
        }
    }
    // layer 2: K=32, F=64, NCF=8 (4096 elems)
    {
        const int K = 32, F = 64, NCF = 8;
        if (idx < K * 2 * F) {
            int frag = idx >> 9, within = idx & 511, lane = within >> 3, j = within & 7;
            int kf = frag / NCF, cf = frag % NCF;
            int k = kf * 32 + (lane >> 4) * 8 + j;
            int c = cf * 16 + (lane & 15);
            float v = (c < F) ? Wt2[c * K + k]
                              : (Wp2[(c - F) * K + k] - Wt2[(c - F) * K + k]);
            wsz2[idx] = __float2half(v);
        }
        if (idx < F) qb2[idx] = bt2[idx] + bp2[idx];
    }
    // layer 3: K=64, F=64, NCF=8 (8192 elems)
    {
        const int K = 64, F = 64, NCF = 8;
        if (idx < K * 2 * F) {
            int frag = idx >> 9, within = idx & 511, lane = within >> 3, j = within & 7;
            int kf = frag / NCF, cf = frag % NCF;
            int k = kf * 32 + (lane >> 4) * 8 + j;
            int c = cf * 16 + (lane & 15);
            float v = (c < F) ? Wt3[c * K + k]
                              : (Wp3[(c - F) * K + k] - Wt3[(c - F) * K + k]);
            wsz3[idx] = __float2half(v);
        }
        if (idx < F) qb3[idx] = bt3[idx] + bp3[idx];
    }
}

// ---------- binned CSR build (padded buckets, no global scan) ----------
// bucket = dst >> 7. Packed edge: (src << 7) | (dst & 127).
__global__ __launch_bounds__(256) void scatter_kernel(const int* __restrict__ esrc,
                                                      const int* __restrict__ edst,
                                                      int* __restrict__ cursor,
                                                      unsigned* __restrict__ binned, int E) {
    __shared__ int hist[NB_BUCKETS];
    __shared__ int lbase[NB_BUCKETS];
    __shared__ unsigned pk[SCAT_CHUNK];
    __shared__ unsigned short bk[SCAT_CHUNK];
    int begE = blockIdx.x * SCAT_CHUNK;
    int endE = min(begE + SCAT_CHUNK, E);
    int n = endE - begE;
    for (int i = threadIdx.x; i < NB_BUCKETS; i += 256) hist[i] = 0;
    __syncthreads();
    for (int i = threadIdx.x; i < n; i += 256) {
        int d = edst[begE + i];
        int s = esrc[begE + i];
        int b = d >> 7;
        pk[i] = ((unsigned)s << 7) | (unsigned)(d & 127);
        bk[i] = (unsigned short)b;
        atomicAdd(&hist[b], 1);
    }
    __syncthreads();
    for (int i = threadIdx.x; i < NB_BUCKETS; i += 256) {
        int c = hist[i];
        lbase[i] = c ? (i * BUCKET_PAD + atomicAdd(&cursor[i], c)) : 0;
        hist[i] = 0;  // reuse as local cursor
    }
    __syncthreads();
    for (int i = threadIdx.x; i < n; i += 256) {
        int b = bk[i];
        int pos = lbase[b] + atomicAdd(&hist[b], 1);
        binned[pos] = pk[i];
    }
}

// one block per bucket: LDS-local CSR build, coalesced csr/beg/end writes.
__global__ __launch_bounds__(256) void bucket_build_kernel(const unsigned* __restrict__ binned,
                                                           const int* __restrict__ bcount,
                                                           int* __restrict__ begs,
                                                           int* __restrict__ ends,
                                                           int* __restrict__ csr) {
    __shared__ unsigned stage[BUCKET_CAP];
    __shared__ int srcLDS[BUCKET_CAP];
    __shared__ int cnt[BUCKET_NODES];
    __shared__ int sc[BUCKET_NODES];
    __shared__ int loff[BUCKET_NODES];

    int b = blockIdx.x;
    int ebeg = b * BUCKET_PAD;
    int ne = min(bcount[b], BUCKET_CAP);
    int tid = threadIdx.x;

    if (tid < BUCKET_NODES) cnt[tid] = 0;
    __syncthreads();
    for (int i = tid; i < ne; i += 256) {
        unsigned e = binned[ebeg + i];
        stage[i] = e;
        atomicAdd(&cnt[e & 127], 1);
    }
    __syncthreads();
    int v = (tid < BUCKET_NODES) ? cnt[tid] : 0;
    if (tid < BUCKET_NODES) sc[tid] = v;
    __syncthreads();
    for (int off = 1; off < BUCKET_NODES; off <<= 1) {
        int u = (tid < BUCKET_NODES && tid >= off) ? sc[tid - off] : 0;
        __syncthreads();
        if (tid < BUCKET_NODES) sc[tid] += u;
        __syncthreads();
    }
    if (tid < BUCKET_NODES) {
        loff[tid] = sc[tid] - v;
        cnt[tid] = 0;
    }
    __syncthreads();
    int gnode = b * BUCKET_NODES + tid;
    if (tid < BUCKET_NODES && gnode < N_NODES) {
        begs[gnode] = ebeg + loff[tid];
        ends[gnode] = ebeg + loff[tid] + v;
    }
    for (int i = tid; i < ne; i += 256) {
        unsigned e = stage[i];
        int ln = e & 127;
        int slot = loff[ln] + atomicAdd(&cnt[ln], 1);
        srcLDS[slot] = (int)(e >> 7);
    }
    __syncthreads();
    for (int i = tid; i < ne; i += 256) csr[ebeg + i] = srcLDS[i];
}

// ---------- A-fragment loaders ----------
template <int K>
static __device__ __forceinline__ f16x8 load_afrag(const __half* __restrict__ x,
                                                   size_t rowIdx, int kOff) {
    return *reinterpret_cast<const f16x8*>(x + rowIdx * K + kOff);
}
template <int K>
static __device__ __forceinline__ f16x8 load_afrag(const float* __restrict__ x,
                                                   size_t rowIdx, int kOff) {
    const float* xr = x + rowIdx * K + kOff;
    float4 a0 = *reinterpret_cast<const float4*>(xr);
    float4 a1 = *reinterpret_cast<const float4*>(xr + 4);
    f16x8 a;
    a[0] = (_Float16)a0.x; a[1] = (_Float16)a0.y; a[2] = (_Float16)a0.z; a[3] = (_Float16)a0.w;
    a[4] = (_Float16)a1.x; a[5] = (_Float16)a1.y; a[6] = (_Float16)a1.z; a[7] = (_Float16)a1.w;
    return a;
}

// ---------- MFMA transform: [100000 x K] @ [K x 2F] -> t (fp16), q+qbias (fp16) ----------
template <int K, int F, typename IT>
__global__ __launch_bounds__(256) void transform_mfma(
        const IT* __restrict__ x, const __half* __restrict__ wsz,
        const float* __restrict__ qb,
        __half* __restrict__ t, __half* __restrict__ q) {
    constexpr int NKF = K / 32;
    constexpr int NCF = (2 * F) / 16;
    constexpr int NTILES = N_NODES / 16;  // 6250

    int lane = threadIdx.x & 63;
    int wid = blockIdx.x * 4 + (threadIdx.x >> 6);
    int nWaves = gridDim.x * 4;

    f16x8 bfrag[NKF][NCF];
#pragma unroll
    for (int kf = 0; kf < NKF; kf++)
#pragma unroll
        for (int cf = 0; cf < NCF; cf++)
            bfrag[kf][cf] = *reinterpret_cast<const f16x8*>(
                wsz + ((size_t)(kf * NCF + cf) * 64 + lane) * 8);

    int row = lane & 15;
    int kq = lane >> 4;
    int col = lane & 15;
    int rbase = (lane >> 4) * 4;

    for (int tile = wid; tile < NTILES; tile += nWaves) {
        size_t nodeBase = (size_t)tile * 16;

        f32x4 acc[NCF];
#pragma unroll
        for (int cf = 0; cf < NCF; cf++) acc[cf] = (f32x4){0.f, 0.f, 0.f, 0.f};

#pragma unroll
        for (int kf = 0; kf < NKF; kf++) {
            f16x8 a = load_afrag<K>(x, nodeBase + row, kf * 32 + kq * 8);
#pragma unroll
            for (int cf = 0; cf < NCF; cf++)
                acc[cf] = __builtin_amdgcn_mfma_f32_16x16x32_f16(a, bfrag[kf][cf], acc[cf], 0, 0, 0);
        }

#pragma unroll
        for (int cf = 0; cf < NCF; cf++) {
            int c = cf * 16 + col;
            if (c < F) {
#pragma unroll
                for (int r = 0; r < 4; r++) {
                    size_t node = nodeBase + rbase + r;
                    t[node * F + c] = __float2half(acc[cf][r]);
                }
            } else {
                float qbv = qb[c - F];
#pragma unroll
                for (int r = 0; r < 4; r++) {
                    size_t node = nodeBase + rbase + r;
                    q[node * F + (c - F)] = __float2half(acc[cf][r] + qbv);
                }
            }
        }
    }
}

// ---------- edge max + combine + ELU (uint4 = 8-channel gathers) ----------
// out[d][c] = indeg(d)>0 ? elu(t[d][c] + max_{s in in(d)} q[s][c]) : 0
template <int F>
__global__ __launch_bounds__(256) void edgemax_kernel(
        const uint4* __restrict__ t16, const uint4* __restrict__ q16,  // [N][F/8]
        const int* __restrict__ begs, const int* __restrict__ ends,
        const int* __restrict__ csr,
        uint4* __restrict__ out, int N) {
    constexpr int NPG = F / 8;      // threads per node (8 channels each)
    constexpr int G = 256 / NPG;    // nodes per block
    int g = threadIdx.x / NPG;
    int cp = threadIdx.x % NPG;
    int nd = blockIdx.x * G + g;
    if (nd >= N) return;
    int beg = begs[nd], end = ends[nd];

    uint4 mneg = {HALF2_NEG_INF, HALF2_NEG_INF, HALF2_NEG_INF, HALF2_NEG_INF};
    uint4 m0 = mneg, m1 = mneg;
    int i = beg;
    for (; i + 1 < end; i += 2) {
        int s0 = csr[i], s1 = csr[i + 1];
        uint4 v0 = q16[(size_t)s0 * NPG + cp];
        uint4 v1 = q16[(size_t)s1 * NPG + cp];
        m0 = pkmax4(m0, v0);
        m1 = pkmax4(m1, v1);
    }
    if (i < end) {
        m0 = pkmax4(m0, q16[(size_t)csr[i] * NPG + cp]);
    }
    uint4 m = pkmax4(m0, m1);

    uint4 res;
    if (beg < end) {
        uint4 tv = t16[(size_t)nd * NPG + cp];
        unsigned* mp = &m.x;
        unsigned* tp = &tv.x;
        unsigned* rp = &res.x;
#pragma unroll
        for (int w = 0; w < 4; w++) {
            float2 mf = __half22float2(__builtin_bit_cast(__half2, mp[w]));
            float2 tf = __half22float2(__builtin_bit_cast(__half2, tp[w]));
            float rx = elu_f(tf.x + mf.x);
            float ry = elu_f(tf.y + mf.y);
            rp[w] = __builtin_bit_cast(unsigned, __floats2half2_rn(rx, ry));
        }
    } else {
        res = (uint4){0u, 0u, 0u, 0u};
    }
    out[(size_t)nd * NPG + cp] = res;
}

// ---------- graph max pooling (fp16 input) ----------
__global__ void pool_kernel(const __half* __restrict__ x, const int* __restrict__ gid,
                            unsigned* __restrict__ pooled, int N) {
    const int CHUNK = 64;
    int wave = (blockIdx.x * blockDim.x + threadIdx.x) >> 6;
    int lane = threadIdx.x & 63;
    int start = wave * CHUNK;
    if (start >= N) return;
    int end = min(start + CHUNK, N);
    float m = -INFINITY;
    int cur = gid[start];
    for (int n = start; n < end; n++) {
        int g = gid[n];
        if (g != cur) {
            atomicMax(&pooled[cur * 64 + lane], fmap(m));
            cur = g;
            m = -INFINITY;
        }
        m = fmaxf(m, __half2float(x[(size_t)n * 64 + lane]));
    }
    atomicMax(&pooled[cur * 64 + lane], fmap(m));
}

// ---------- FC head + log_softmax, one block (64 threads) per graph ----------
__global__ __launch_bounds__(64) void fc_kernel(
        const unsigned* __restrict__ pooled,
        const float* __restrict__ Wf1, const float* __restrict__ bf1,
        const float* __restrict__ Wf2, const float* __restrict__ bf2,
        const float* __restrict__ Wf3, const float* __restrict__ bf3,
        float* __restrict__ out) {
    int g = blockIdx.x;
    int c = threadIdx.x;
    __shared__ float x0[64], h1[64], h2[32], h3[10];

    unsigned u = pooled[g * 64 + c];
    x0[c] = (u == NEG_INF_MAPPED) ? 0.f : funmap(u);
    __syncthreads();

    float a = bf1[c];
#pragma unroll 8
    for (int k = 0; k < 64; k++) a = fmaf(Wf1[c * 64 + k], x0[k], a);
    h1[c] = elu_f(a);
    __syncthreads();

    if (c < 32) {
        float a2 = bf2[c];
#pragma unroll 8
        for (int k = 0; k < 64; k++) a2 = fmaf(Wf2[c * 64 + k], h1[k], a2);
        h2[c] = elu_f(a2);
    }
    __syncthreads();

    if (c < 10) {
        float a3 = bf3[c];
#pragma unroll 8
        for (int k = 0; k < 32; k++) a3 = fmaf(Wf3[c * 32 + k], h2[k], a3);
        h3[c] = a3;
    }
    __syncthreads();

    if (c < 10) {
        float mx = h3[0];
#pragma unroll
        for (int j = 1; j < 10; j++) mx = fmaxf(mx, h3[j]);
        float s = 0.f;
#pragma unroll
        for (int j = 0; j < 10; j++) s += expf(h3[j] - mx);
        out[g * 10 + c] = h3[c] - mx - logf(s);
    }
}

// ---------- launch ----------
extern "C" void kernel_launch(void* const* d_in, const int* in_sizes, int n_in,
                              void* d_out, int out_size, void* d_ws, size_t ws_size,
                              hipStream_t stream) {
    const float* atom = (const float*)d_in[0];
    const int* esrc = (const int*)d_in[1];
    const int* edst = (const int*)d_in[2];
    const int* gid  = (const int*)d_in[3];
    const float* Wt1 = (const float*)d_in[4];
    const float* bt1 = (const float*)d_in[5];
    const float* Wp1 = (const float*)d_in[6];
    const float* bp1 = (const float*)d_in[7];
    const float* bng = (const float*)d_in[8];
    const float* bnb = (const float*)d_in[9];
    const float* bnm = (const float*)d_in[10];
    const float* bnv = (const float*)d_in[11];
    const float* Wt2 = (const float*)d_in[12];
    const float* bt2 = (const float*)d_in[13];
    const float* Wp2 = (const float*)d_in[14];
    const float* bp2 = (const float*)d_in[15];
    const float* Wt3 = (const float*)d_in[16];
    const float* bt3 = (const float*)d_in[17];
    const float* Wp3 = (const float*)d_in[18];
    const float* bp3 = (const float*)d_in[19];
    const float* Wf1 = (const float*)d_in[20];
    const float* bf1 = (const float*)d_in[21];
    const float* Wf2 = (const float*)d_in[22];
    const float* bf2 = (const float*)d_in[23];
    const float* Wf3 = (const float*)d_in[24];
    const float* bf3 = (const float*)d_in[25];

    // workspace carve-up
    char* p = (char*)d_ws;
    auto alloc = [&](size_t bytes) -> void* {
        void* r = (void*)p;
        p += (bytes + 255) & ~(size_t)255;
        return r;
    };
    int* begs        = (int*)alloc(sizeof(int) * N_NODES);
    int* ends        = (int*)alloc(sizeof(int) * N_NODES);
    int* cursor      = (int*)alloc(sizeof(int) * NB_BUCKETS);
    unsigned* binned = (unsigned*)alloc(sizeof(unsigned) * NB_BUCKETS * BUCKET_PAD);
    int* csr         = (int*)alloc(sizeof(int) * NB_BUCKETS * BUCKET_PAD);
    __half* wsz1 = (__half*)alloc(sizeof(__half) * 128 * 64);
    __half* wsz2 = (__half*)alloc(sizeof(__half) * 32 * 128);
    __half* wsz3 = (__half*)alloc(sizeof(__half) * 64 * 128);
    float* qb1   = (float*)alloc(sizeof(float) * 32);
    float* qb2   = (float*)alloc(sizeof(float) * 64);
    float* qb3   = (float*)alloc(sizeof(float) * 64);
    __half* tbuf = (__half*)alloc(sizeof(__half) * (size_t)N_NODES * 64);
    __half* qbuf = (__half*)alloc(sizeof(__half) * (size_t)N_NODES * 64);
    __half* xh   = (__half*)alloc(sizeof(__half) * (size_t)N_NODES * 64);
    unsigned* pooled = (unsigned*)alloc(sizeof(unsigned) * N_GRAPHS * 64);

    // prep (zeroes cursor + inits pooled) + CSR build
    prep_kernel<<<32, 256, 0, stream>>>(Wt1, bt1, Wp1, bp1, bng, bnb, bnm, bnv,
                                        Wt2, bt2, Wp2, bp2, Wt3, bt3, Wp3, bp3,
                                        wsz1, qb1, wsz2, qb2, wsz3, qb3, cursor, pooled);
    scatter_kernel<<<(N_EDGES + SCAT_CHUNK - 1) / SCAT_CHUNK, 256, 0, stream>>>(
        esrc, edst, cursor, binned, N_EDGES);
    bucket_build_kernel<<<NB_BUCKETS, 256, 0, stream>>>(binned, cursor, begs, ends, csr);

    // layer 1: 128 -> 32 (BN folded), fp32 input
    transform_mfma<128, 32, float><<<1024, 256, 0, stream>>>(atom, wsz1, qb1, tbuf, qbuf);
    edgemax_kernel<32><<<(N_NODES + 63) / 64, 256, 0, stream>>>(
        (const uint4*)tbuf, (const uint4*)qbuf, begs, ends, csr, (uint4*)xh, N_NODES);

    // layer 2: 32 -> 64, fp16 input
    transform_mfma<32, 64, __half><<<1024, 256, 0, stream>>>(xh, wsz2, qb2, tbuf, qbuf);
    edgemax_kernel<64><<<(N_NODES + 31) / 32, 256, 0, stream>>>(
        (const uint4*)tbuf, (const uint4*)qbuf, begs, ends, csr, (uint4*)xh, N_NODES);

    // layer 3: 64 -> 64, fp16 input
    transform_mfma<64, 64, __half><<<1024, 256, 0, stream>>>(xh, wsz3, qb3, tbuf, qbuf);
    edgemax_kernel<64><<<(N_NODES + 31) / 32, 256, 0, stream>>>(
        (const uint4*)tbuf, (const uint4*)qbuf, begs, ends, csr, (uint4*)xh, N_NODES);

    // graph pooling
    {
        int waves = (N_NODES + 63) / 64;
        int blocks = (waves + 3) / 4;
        pool_kernel<<<blocks, 256, 0, stream>>>(xh, gid, pooled, N_NODES);
    }

    // FC head
    fc_kernel<<<N_GRAPHS, 64, 0, stream>>>(pooled, Wf1, bf1, Wf2, bf2, Wf3, bf3, (float*)d_out);
}